// Round 13
// baseline (182.031 us; speedup 1.0000x reference)
//
#include <hip/hip_runtime.h>
#include <hip/hip_bf16.h>
#include <stdint.h>

#define NF 51
#define NF2 (51*51)
#define WIN 100
#define EMB 12
#define FIN 112
#define HID 60
#define NPRUNE 1561
#define SORTN 4096

// ws: prune -> forward handoff only
#define WS_ADJ   0        // f16 [64][72] plain adj rows (k<51 real; else 0)
#define WS_D     9216     // f32 [51][112] D = norm_adj@C_emb + gcn_b (col<100 else 0)
#define WS_FLAG  32064    // int ready-flag (memsetAsync to 0 each launch)

// forward LDS (r10 layout, unchanged)
#define LDS_WX   0          // f16 [112][136]
#define LDS_W1   30464      // f16 [64][136]
#define LDS_R1X  47872      // f16 [115][136]  sX
#define LDS_R1H  79152      // f16 [115][136]  h2 (also w2 build scratch pre-loop)
#define LDS_R2   110432     // f16 yT [2][112][72] / h3 [115][72] (aliased)
#define LDS_TOTAL 142688

typedef _Float16 f16;
typedef _Float16 f16x8 __attribute__((ext_vector_type(8)));
typedef _Float16 f16x4 __attribute__((ext_vector_type(4)));
typedef float f32x4 __attribute__((ext_vector_type(4)));

__device__ __forceinline__ float fast_tanh(float x) {
  float xa = fminf(fmaxf(x, -15.f), 15.f);
  float e = __expf(2.f * xa);
  return (e - 1.f) * __builtin_amdgcn_rcpf(e + 1.f);
}

// T4 barrier: LDS-visibility wait only; vmcnt NOT drained.
#define BAR() do { asm volatile("s_waitcnt lgkmcnt(0)" ::: "memory"); \
  __builtin_amdgcn_s_barrier(); asm volatile("" ::: "memory"); } while (0)

// prune scratch overlaid on the activation LDS region (dead pre-loop).
// ~53.8 KB, fits in [LDS_R1X, LDS_TOTAL) = 94.8 KB.
struct PruneScr {
  float sA[NF * 52];
  unsigned long long sKey[SORTN];
  float sNrm[NF];
  float sDinv[NF];
  float sRow[NF];
  float sCol[NF];
  float sRowS[NF];
  float sColS[NF];
  float sEmb[NF * EMB];
  float sE2[NF * EMB];
  unsigned long long sSusp[64];
  unsigned char sMask[NF2];
  int sCand[256];
  int sCnt[17];
  int sNS;
  int sNC;
  int sTotal;
};

// ---------------- Fused kernel: block 0 = prune + forward; all = forward ----
// 256 blocks x 512 thr (1 block/CU, 8 waves). Forward body IDENTICAL to the
// banked r10/r12 kernel (115.3us, VGPR 124, no spill): w1 in LDS, adj/w2/D/
// b1/b2 in registers (~136 persistent — the allocator's feasible edge).
// Fusion only removes the separate prune launch: every block builds wxT/w1T
// (LDS) + w2f (regs, via sH scratch) from GLOBAL while block 0 runs the
// prune in overlaid LDS scratch and publishes adjT/D to ws + release-flag.
__global__ __launch_bounds__(512, 1) void fused_kernel(
    const float* __restrict__ x, const float* __restrict__ embed,
    const float* __restrict__ gcn_w, const float* __restrict__ gcn_b,
    const float* __restrict__ w1, const float* __restrict__ b1g,
    const float* __restrict__ w2, const float* __restrict__ b2g,
    void* __restrict__ ws, float* __restrict__ out, int nPairs, int ppb) {
  __shared__ __align__(16) char smem[LDS_TOTAL];
  f16* wxT = (f16*)(smem + LDS_WX);
  f16* w1T = (f16*)(smem + LDS_W1);
  f16* sX  = (f16*)(smem + LDS_R1X);   // [115][136] x rows
  f16* sH  = (f16*)(smem + LDS_R1H);   // [115][136] h2 rows
  f16* yT  = (f16*)(smem + LDS_R2);    // [2][112][72]
  f16* h3  = (f16*)(smem + LDS_R2);    // [115][72] (aliases yT)

  const int t = threadIdx.x;
  const int bid = blockIdx.x;
  const int wv = t >> 6, lane = t & 63;
  const int c = lane & 15, g = lane >> 4;
  const int s = wv >> 2, mt = wv & 3;
  const int rowA = 51*s + 16*mt + c;
  char* wsb = (char*)ws;
  int* flagP = (int*)(wsb + WS_FLAG);

  // ---- every block: build wxT + w1T in LDS from global (masked) ----
  for (int u = t; u < 112*136; u += 512) {
    int nn = u / 136, k = u - nn*136;
    wxT[u] = (f16)((nn < WIN && k < WIN) ? gcn_w[nn*FIN + k] : 0.f);
  }
  for (int u = t; u < 64*136; u += 512) {
    int nn = u / 136, k = u - nn*136;
    w1T[u] = (f16)((nn < HID && k < WIN) ? w1[nn*WIN + k] : 0.f);
  }
  // w2 -> sH scratch -> registers (must complete before block-0 prune
  // overwrites the scratch region)
  {
    f16* w2s = sH;
    for (int u = t; u < 112*72; u += 512) {
      int nn = u / 72, k = u - nn*72;
      w2s[u] = (f16)((nn < WIN && k < HID) ? w2[nn*HID + k] : 0.f);
    }
  }
  __syncthreads();
  f16x8 w2f[7][2];
  #pragma unroll
  for (int N = 0; N < 7; N++) {
    const f16* ap = &sH[(16*N + c)*72 + 8*g];
    w2f[N][0] = *(const f16x8*)(ap + 0);
    w2f[N][1] = *(const f16x8*)(ap + 32);
  }
  __syncthreads();

  // issue first x prefetch (latency hidden under prune / spin)
  const int pair0 = bid * ppb;
  float4 p0, p1, p2, p3, p4;
  if (pair0 < nPairs) {
    const float4* xb = (const float4*)(x + (size_t)pair0 * 10200);
    p0 = xb[t]; p1 = xb[t+512]; p2 = xb[t+1024]; p3 = xb[t+1536];
    if (t < 502) p4 = xb[t+2048];
  }

  // ================= block 0: prune (scratch overlays activations) ==========
  if (bid == 0) {
    PruneScr* P = (PruneScr*)(smem + LDS_R1X);
    for (int u = t; u < NF * EMB; u += 512) P->sEmb[u] = embed[u];
    for (int u = t; u < NF2; u += 512) P->sMask[u] = 0;
    if (t == 0) { P->sNS = 0; P->sNC = 0; P->sTotal = 0; }
    __syncthreads();
    if (t < NF) {
      float ssum = 0.f;
      for (int e = 0; e < EMB; e++) { float w = P->sEmb[t*EMB + e]; ssum += w * w; }
      P->sNrm[t] = sqrtf(ssum);
    }
    __syncthreads();
    for (int u = t; u < NF2; u += 512) {
      int r = u / NF, cc = u % NF;
      float d = 0.f;
      for (int e = 0; e < EMB; e++) d += P->sEmb[r*EMB + e] * P->sEmb[cc*EMB + e];
      P->sA[r*52 + cc] = d / (P->sNrm[r] * P->sNrm[cc]);
    }
    __syncthreads();
    if (t < NF) {
      float rs = 0.f, cs = 0.f;
      for (int j = 0; j < NF; j++) { rs += P->sA[t*52 + j]; cs += P->sA[j*52 + t]; }
      P->sRow[t] = rs; P->sCol[t] = cs;
    }
    __syncthreads();
    // STAGE A: rejection requires visit-sum<=v on BOTH axes; sums only grow.
    {
      int myCnt = 0;
      for (int u = t; u < NF2; u += 512) {
        int r = u / NF, cc = u % NF;
        float v = P->sA[r*52 + cc];
        if (v < 0.f) {
          myCnt++;
          if (P->sRow[r] <= v && P->sCol[cc] <= v) {
            int slot = atomicAdd(&P->sNC, 1);
            if (slot < 256) P->sCand[slot] = u;
          }
        }
      }
      if (myCnt) atomicAdd(&P->sTotal, myCnt);
    }
    __syncthreads();
    // STAGE B: prefix-sharpened bound; survivors are true suspects.
    if (P->sNC <= 256) {
      const int nC = P->sNC;
      for (int i = t; i < nC; i += 512) {
        int u = P->sCand[i];
        int r = u / NF, cc = u - r*NF;
        float v = P->sA[r*52 + cc];
        float Pr = 0.f, Pc = 0.f;
        for (int j = 0; j < NF; j++) {
          float a = P->sA[r*52 + j];
          if (a < 0.f && (a < v || (a == v && r*NF + j < u))) Pr -= a;
          float bb = P->sA[j*52 + cc];
          if (bb < 0.f && (bb < v || (bb == v && j*NF + cc < u))) Pc -= bb;
        }
        bool okS = ((P->sRow[r] + Pr - v) > 0.f) || ((P->sCol[cc] + Pc - v) > 0.f);
        if (!okS) {
          int slot = atomicAdd(&P->sNS, 1);
          if (slot < 64) {
            unsigned int bb = __float_as_uint(v);
            P->sSusp[slot] = ((unsigned long long)(~bb) << 32) | (unsigned int)u;
            P->sMask[u] = 1;
          }
        }
      }
    }
    __syncthreads();
    const bool fastPath = (P->sTotal > 0) && (P->sTotal <= NPRUNE) &&
                          (P->sNC <= 256) && (P->sNS <= 64);
    if (fastPath) {
      if (t < 64) {
        const int ln = t;
        float mx = -3.0e38f;
        for (int u = ln; u < NF2; u += 64) mx = fmaxf(mx, P->sA[(u / NF)*52 + (u % NF)]);
        for (int o = 32; o > 0; o >>= 1) mx = fmaxf(mx, __shfl_xor(mx, o, 64));
        if (ln < NF) { P->sRowS[ln] = 0.f; P->sColS[ln] = 0.f; }
        const int nS = P->sNS;
        unsigned long long key = (ln < nS) ? P->sSusp[ln] : ~0ull;
        for (int k = 2; k <= 64; k <<= 1) {
          for (int j = k >> 1; j > 0; j >>= 1) {
            unsigned long long other = __shfl_xor(key, j, 64);
            bool up = ((ln & k) == 0);
            bool takeMin = (((ln & j) == 0) == up);
            unsigned long long mn = key < other ? key : other;
            unsigned long long mxk = key < other ? other : key;
            key = takeMin ? mn : mxk;
          }
        }
        for (int kk = 0; kk < nS; kk++) {
          unsigned long long kv = __shfl(key, kk, 64);
          unsigned int mb = (unsigned int)(kv >> 32);
          unsigned int idx = (unsigned int)kv;
          float v = __uint_as_float(~mb);
          int r = (int)(idx / NF), cc = (int)(idx % NF);
          float pr = 0.f, pc = 0.f;
          if (ln < NF) {
            float a = P->sA[r*52 + ln];
            if (a < 0.f && !P->sMask[r*NF + ln] &&
                (a < v || (a == v && (unsigned)(r*NF + ln) < idx))) pr = -a;
            float bb = P->sA[ln*52 + cc];
            if (bb < 0.f && !P->sMask[ln*NF + cc] &&
                (bb < v || (bb == v && (unsigned)(ln*NF + cc) < idx))) pc = -bb;
          }
          for (int o = 32; o > 0; o >>= 1) {
            pr += __shfl_xor(pr, o, 64);
            pc += __shfl_xor(pc, o, 64);
          }
          float sumR = P->sRow[r] + pr + P->sRowS[r];
          float sumC = P->sCol[cc] + pc + P->sColS[cc];
          bool ok = ((sumR - v) > 0.f) || ((sumC - v) > 0.f);
          if (ln == 0) {
            if (ok) { P->sA[r*52 + cc] = 0.f; P->sRowS[r] += -v;     P->sColS[cc] += -v; }
            else    { P->sA[r*52 + cc] = mx;  P->sRowS[r] += mx - v; P->sColS[cc] += mx - v; }
          }
        }
      }
      __syncthreads();
      for (int u = t; u < NF2; u += 512) {
        int r = u / NF, cc = u % NF;
        if (P->sA[r*52 + cc] < 0.f) P->sA[r*52 + cc] = 0.f;
      }
    } else {
      // SLOW PATH: compaction + bitonic sort + ballot walk
      int myCnt = 0;
      for (int u = t; u < NF2; u += 512)
        myCnt += (P->sA[(u / NF)*52 + (u % NF)] < 0.f) ? 1 : 0;
      int incl = myCnt;
      for (int o = 1; o < 64; o <<= 1) {
        int nb = __shfl_up(incl, o, 64);
        if ((t & 63) >= o) incl += nb;
      }
      if ((t & 63) == 63) P->sCnt[t >> 6] = incl;
      __syncthreads();
      if (t == 0) {
        int run = 0;
        for (int j = 0; j < 8; j++) { int v = P->sCnt[j]; P->sCnt[8 + j] = run; run += v; }
        P->sCnt[16] = run;
      }
      __syncthreads();
      const int total = P->sCnt[16];
      const int n = (total <= 2048) ? 2048 : SORTN;
      {
        int cpos = P->sCnt[8 + (t >> 6)] + (incl - myCnt);
        for (int u = t; u < NF2; u += 512) {
          float v = P->sA[(u / NF)*52 + (u % NF)];
          if (v < 0.f) {
            unsigned int bb = __float_as_uint(v);
            P->sKey[cpos++] = ((unsigned long long)(~bb) << 32) | (unsigned int)u;
          }
        }
        for (int u = total + t; u < n; u += 512) P->sKey[u] = ~0ull;
      }
      __syncthreads();
      for (int kk = 2; kk <= n; kk <<= 1) {
        for (int jj = kk >> 1; jj > 0; jj >>= 1) {
          for (int u = t; u < n; u += 512) {
            int l = u ^ jj;
            if (l > u) {
              unsigned long long a = P->sKey[u], bb = P->sKey[l];
              bool up = ((u & kk) == 0);
              if ((a > bb) == up) { P->sKey[u] = bb; P->sKey[l] = a; }
            }
          }
          __syncthreads();
        }
      }
      if (t < 64) {
        const int ln = t;
        float mx = -3.0e38f;
        for (int u = ln; u < NF2; u += 64) mx = fmaxf(mx, P->sA[(u / NF)*52 + (u % NF)]);
        for (int o = 32; o > 0; o >>= 1) mx = fmaxf(mx, __shfl_xor(mx, o, 64));
        int pruned = 0, pos = 0;
        bool toP2 = false;
        while (pruned < NPRUNE && !toP2) {
          int myi = pos + ln;
          unsigned long long kv = (myi < n) ? P->sKey[myi] : ~0ull;
          unsigned int mb  = (unsigned int)(kv >> 32);
          unsigned int idx = (unsigned int)kv;
          unsigned int vb  = (mb & 0x80000000u) ? (mb & 0x7FFFFFFFu) : ~mb;
          float v = __uint_as_float(vb);
          bool elig = (v < 0.f) && (idx < (unsigned)NF2);
          int r = 0, c2 = 0; bool okl = false;
          if (elig) {
            r = (int)(idx / NF); c2 = (int)(idx % NF);
            float sr = P->sRow[r], sc = P->sCol[c2];
            okl = ((sr - v) > 0.f) || ((sc - v) > 0.f);
          }
          unsigned long long bal = __ballot(okl);
          unsigned long long nb = ~bal;
          int nok = (nb == 0ull) ? 64 : (int)__builtin_ctzll(nb);
          int rem = NPRUNE - pruned;
          int take = nok < rem ? nok : rem;
          if (ln < take) {
            P->sA[r*52 + c2] = 0.f;
            atomicAdd(&P->sRow[r], -v);
            atomicAdd(&P->sCol[c2], -v);
          }
          pruned += take; pos += take;
          if (pruned >= NPRUNE) break;
          if (take == 64) continue;
          unsigned int bvb = (unsigned int)__builtin_amdgcn_readlane((int)vb, take);
          int bidx = __builtin_amdgcn_readlane((int)idx, take);
          float bv = __uint_as_float(bvb);
          if (!(bv < 0.f) || bidx >= NF2) { toP2 = true; break; }
          int br = bidx / NF, bc = bidx % NF;
          float sr = P->sRow[br], sc = P->sCol[bc];
          bool ok = ((sr - bv) > 0.f) || ((sc - bv) > 0.f);
          if (ok) {
            if (ln == 0) {
              P->sA[br*52 + bc] = 0.f;
              P->sRow[br] = sr - bv; P->sCol[bc] = sc - bv;
            }
            pruned++; pos++;
          } else {
            if (ln == 0) {
              P->sA[br*52 + bc] = mx;
              P->sRow[br] = sr + (mx - bv); P->sCol[bc] = sc + (mx - bv);
            }
            pos++;
          }
        }
        if (toP2) {
          for (int guard = 0; guard < 40000 && pruned < NPRUNE; guard++) {
            float bv = 3.0e38f; int bidx = NF2;
            for (int u = ln; u < NF2; u += 64) {
              float v = P->sA[(u / NF)*52 + (u % NF)];
              if (v < bv) { bv = v; bidx = u; }
            }
            for (int o = 32; o > 0; o >>= 1) {
              float ov = __shfl_xor(bv, o, 64);
              int  oi = __shfl_xor(bidx, o, 64);
              if (ov < bv || (ov == bv && oi < bidx)) { bv = ov; bidx = oi; }
            }
            int br = bidx / NF, bc = bidx % NF;
            float sr = P->sRow[br], sc = P->sCol[bc];
            bool ok = ((sr - bv) > 0.f) || ((sc - bv) > 0.f);
            if (ok) {
              if (bv == 0.f) break;
              if (ln == 0) { P->sA[br*52+bc] = 0.f; P->sRow[br] = sr - bv; P->sCol[bc] = sc - bv; }
              pruned++;
            } else {
              if (bv == mx) break;
              if (ln == 0) { P->sA[br*52+bc] = mx; P->sRow[br] = sr + (mx-bv); P->sCol[bc] = sc + (mx-bv); }
            }
          }
        }
      }
    }
    __syncthreads();
    if (t < NF) {
      float deg = 0.f;
      for (int j = 0; j < NF; j++) {
        float a = P->sA[t*52 + j];
        float bin = (a != 0.f) ? 1.f : 0.f;
        if (j == t) bin += 1.f;
        deg += bin;
      }
      P->sDinv[t] = 1.f / sqrtf(deg);
    }
    __syncthreads();
    float* sN = (float*)P->sKey;   // sKey dead; reuse as norm_adj [51][52]
    for (int u = t; u < NF * 52; u += 512) {
      int r = u / 52, cc = u % 52;
      float v = 0.f;
      if (cc < NF) {
        float a = P->sA[r*52 + cc];
        float bin = (a != 0.f) ? 1.f : 0.f;
        if (r == cc) bin += 1.f;
        v = P->sDinv[r] * bin * P->sDinv[cc];
      }
      sN[u] = v;
    }
    __syncthreads();
    for (int u = t; u < NF * EMB; u += 512) {
      int i = u / EMB, e = u % EMB;
      float s2 = 0.f;
      for (int j = 0; j < NF; j++) s2 += sN[i*52 + j] * P->sEmb[j*EMB + e];
      P->sE2[u] = s2;
    }
    f16* adjW = (f16*)(wsb + WS_ADJ);
    for (int u = t; u < 64*72; u += 512) {
      int r = u / 72, k = u % 72;
      adjW[u] = (f16)((r < NF && k < NF) ? sN[r*52 + k] : 0.f);
    }
    __syncthreads();   // sE2 ready
    float* Dp = (float*)(wsb + WS_D);
    for (int u = t; u < NF * 112; u += 512) {
      int i = u / 112, w = u % 112;
      float s2 = 0.f;
      if (w < WIN) {
        for (int e = 0; e < EMB; e++) s2 += P->sE2[i*EMB + e] * gcn_w[w*FIN + WIN + e];
        s2 += gcn_b[w];
      }
      Dp[u] = s2;
    }
    __syncthreads();
    if (t == 0)
      __hip_atomic_store(flagP, 1, __ATOMIC_RELEASE, __HIP_MEMORY_SCOPE_AGENT);
  }

  if (bid != 0 && t == 0) {
    while (__hip_atomic_load(flagP, __ATOMIC_ACQUIRE, __HIP_MEMORY_SCOPE_AGENT) == 0)
      __builtin_amdgcn_s_sleep(32);
  }
  __syncthreads();   // flag acquired block-wide; prune/scratch region dead

  // zero activation regions (sX/sH/yT)
  {
    f32x4 z = {0.f,0.f,0.f,0.f};
    f32x4* za = (f32x4*)(smem + LDS_R1X);
    #pragma unroll
    for (int u = 0; u < 12; u++) { int i = t + u*512; if (i < 5926) za[i] = z; }
  }

  // ---- register-resident prune-dependent data (r10-identical profile) ----
  const f16* adjG = (const f16*)(wsb + WS_ADJ);
  const float* DG = (const float*)(wsb + WS_D);
  f16x8 adjf[4][2];
  #pragma unroll
  for (int N = 0; N < 4; N++) {
    const f16* bp = &adjG[(16*N + c)*72 + 8*g];
    adjf[N][0] = *(const f16x8*)(bp + 0);
    adjf[N][1] = *(const f16x8*)(bp + 32);
  }
  const int s2a = (wv == 7) ? 1 : 0;
  const int wta = (wv == 7) ? 0 : wv;
  const int wtb = wv + 1;                 // s2 = 1, only wv < 6
  float4 dA[4], dB[4];
  {
    const float4 zf = {0.f,0.f,0.f,0.f};
    #pragma unroll
    for (int N = 0; N < 4; N++) {
      int nd = 16*N + c;
      dA[N] = (nd < NF) ? *(const float4*)&DG[nd*112 + 16*wta + 4*g] : zf;
      dB[N] = (wv < 6 && nd < NF) ? *(const float4*)&DG[nd*112 + 16*wtb + 4*g] : zf;
    }
  }
  float4 b1f[4], b2f[7];
  {
    const float4 zf = {0.f,0.f,0.f,0.f};
    #pragma unroll
    for (int N = 0; N < 4; N++) {
      int colb = 16*N + 4*g;
      b1f[N] = (colb < HID) ? *(const float4*)&b1g[colb] : zf;
    }
    #pragma unroll
    for (int N = 0; N < 7; N++) {
      int colb = 16*N + 4*g;
      b2f[N] = (colb < WIN) ? *(const float4*)&b2g[colb] : zf;
    }
  }
  __syncthreads();   // zeros visible block-wide

  // prologue: write sX(pair0)
  if (pair0 < nPairs) {
    #define STV(PV, V) { int row = (V)/25, q4 = ((V)%25)*4; \
      f16x4 hv = {(f16)(PV).x,(f16)(PV).y,(f16)(PV).z,(f16)(PV).w}; \
      *(f16x4*)&sX[row*136 + q4] = hv; }
    STV(p0, t); STV(p1, t+512); STV(p2, t+1024); STV(p3, t+1536);
    if (t < 502) STV(p4, t+2048);
  }

  #pragma unroll 1
  for (int p = 0; p < ppb; p++) {
    const int pairIdx = pair0 + p;
    const bool valid = pairIdx < nPairs;

    BAR();   // bar A: sX(p) ready (written end of prev iter / prologue)

    // issue next pair's prefetch (consumed at iter end; spans S1..S4)
    if (p + 1 < ppb && pairIdx + 1 < nPairs) {
      const float4* xb = (const float4*)(x + (size_t)(pairIdx+1) * 10200);
      p0 = xb[t]; p1 = xb[t+512]; p2 = xb[t+1024]; p3 = xb[t+1536];
      if (t < 502) p4 = xb[t+2048];
    }

    // ---- S1: y = x @ Wx^T ; write yT[s][win][node] (transposed, b64) ----
    if (valid) {
      const f16* aB = &sX[rowA*136];
      const f16x8 a0 = *(const f16x8*)(aB +  0 + 8*g);
      const f16x8 a1 = *(const f16x8*)(aB + 32 + 8*g);
      const f16x8 a2 = *(const f16x8*)(aB + 64 + 8*g);
      const f16x8 a3 = *(const f16x8*)(aB + 96 + 8*g);
      f16* yTs = yT + s*8064;
      const int nodeW = 16*mt + 4*g;
      #pragma unroll
      for (int N = 0; N < 7; N++) {
        const f16* bp = &wxT[(16*N + c)*136 + 8*g];
        f32x4 acc = {0.f,0.f,0.f,0.f};
        acc = __builtin_amdgcn_mfma_f32_16x16x32_f16(a0, *(const f16x8*)(bp +  0), acc, 0, 0, 0);
        acc = __builtin_amdgcn_mfma_f32_16x16x32_f16(a1, *(const f16x8*)(bp + 32), acc, 0, 0, 0);
        acc = __builtin_amdgcn_mfma_f32_16x16x32_f16(a2, *(const f16x8*)(bp + 64), acc, 0, 0, 0);
        acc = __builtin_amdgcn_mfma_f32_16x16x32_f16(a3, *(const f16x8*)(bp + 96), acc, 0, 0, 0);
        const int col = 16*N + c;
        if (mt < 3) {
          f16x4 hv = {(f16)acc[0],(f16)acc[1],(f16)acc[2],(f16)acc[3]};
          *(f16x4*)&yTs[col*72 + nodeW] = hv;
        } else {
          #pragma unroll
          for (int r2 = 0; r2 < 4; r2++)
            if (nodeW + r2 < NF) yTs[col*72 + nodeW + r2] = (f16)acc[r2];
        }
      }
    }
    BAR();   // bar B: yT ready; sX reads done

    // ---- S2 (swapped): h2 = relu(adj @ y + D) -> sH, b64 writes ----
    if (valid) {
      {
        const f16* ap = &yT[s2a*8064 + (16*wta + c)*72 + 8*g];
        const f16x8 a0 = *(const f16x8*)(ap + 0);
        const f16x8 a1 = *(const f16x8*)(ap + 32);
        #pragma unroll
        for (int N = 0; N < 4; N++) {
          f32x4 acc = {0.f,0.f,0.f,0.f};
          acc = __builtin_amdgcn_mfma_f32_16x16x32_f16(a0, adjf[N][0], acc, 0, 0, 0);
          acc = __builtin_amdgcn_mfma_f32_16x16x32_f16(a1, adjf[N][1], acc, 0, 0, 0);
          const int nd = 16*N + c;
          if (nd < NF) {
            const float4 dv = dA[N];
            f16x4 hv = {(f16)fmaxf(acc[0]+dv.x,0.f),(f16)fmaxf(acc[1]+dv.y,0.f),
                        (f16)fmaxf(acc[2]+dv.z,0.f),(f16)fmaxf(acc[3]+dv.w,0.f)};
            *(f16x4*)&sH[(51*s2a + nd)*136 + 16*wta + 4*g] = hv;
          }
        }
      }
      if (wv < 6) {
        const f16* ap = &yT[8064 + (16*wtb + c)*72 + 8*g];
        const f16x8 a0 = *(const f16x8*)(ap + 0);
        const f16x8 a1 = *(const f16x8*)(ap + 32);
        #pragma unroll
        for (int N = 0; N < 4; N++) {
          f32x4 acc = {0.f,0.f,0.f,0.f};
          acc = __builtin_amdgcn_mfma_f32_16x16x32_f16(a0, adjf[N][0], acc, 0, 0, 0);
          acc = __builtin_amdgcn_mfma_f32_16x16x32_f16(a1, adjf[N][1], acc, 0, 0, 0);
          const int nd = 16*N + c;
          if (nd < NF) {
            const float4 dv = dB[N];
            f16x4 hv = {(f16)fmaxf(acc[0]+dv.x,0.f),(f16)fmaxf(acc[1]+dv.y,0.f),
                        (f16)fmaxf(acc[2]+dv.z,0.f),(f16)fmaxf(acc[3]+dv.w,0.f)};
            *(f16x4*)&sH[(51 + nd)*136 + 16*wtb + 4*g] = hv;
          }
        }
      }
    }
    BAR();   // bar C: h2 ready; yT reads done

    // ---- S3 (swapped): h3 = tanh(h2 @ w1^T + b1) -> R2, b64 writes ----
    if (valid) {
      const f16* bB = &sH[rowA*136 + 8*g];
      const f16x8 hb0 = *(const f16x8*)(bB +  0);
      const f16x8 hb1 = *(const f16x8*)(bB + 32);
      const f16x8 hb2 = *(const f16x8*)(bB + 64);
      const f16x8 hb3 = *(const f16x8*)(bB + 96);
      #pragma unroll
      for (int N = 0; N < 4; N++) {
        const f16* ap = &w1T[(16*N + c)*136 + 8*g];
        f32x4 acc = {0.f,0.f,0.f,0.f};
        acc = __builtin_amdgcn_mfma_f32_16x16x32_f16(*(const f16x8*)(ap +  0), hb0, acc, 0, 0, 0);
        acc = __builtin_amdgcn_mfma_f32_16x16x32_f16(*(const f16x8*)(ap + 32), hb1, acc, 0, 0, 0);
        acc = __builtin_amdgcn_mfma_f32_16x16x32_f16(*(const f16x8*)(ap + 64), hb2, acc, 0, 0, 0);
        acc = __builtin_amdgcn_mfma_f32_16x16x32_f16(*(const f16x8*)(ap + 96), hb3, acc, 0, 0, 0);
        const int colb = 16*N + 4*g;
        const float4 bv = b1f[N];
        f16x4 hv = {(f16)fast_tanh(acc[0]+bv.x),(f16)fast_tanh(acc[1]+bv.y),
                    (f16)fast_tanh(acc[2]+bv.z),(f16)fast_tanh(acc[3]+bv.w)};
        *(f16x4*)&h3[rowA*72 + colb] = hv;
      }
    }
    // No barrier: S4 consumes ONLY rows written by this same wave in S3.
    asm volatile("s_waitcnt lgkmcnt(0)" ::: "memory");
    __builtin_amdgcn_sched_barrier(0);

    // ---- S4 (swapped): out = tanh(h3 @ w2^T + b2) -> coalesced float4 ----
    if (valid) {
      const f16* bB = &h3[rowA*72 + 8*g];
      const f16x8 hb0 = *(const f16x8*)(bB +  0);
      const f16x8 hb1 = *(const f16x8*)(bB + 32);
      const bool rowOk = (16*mt + c) < NF;
      float* ob = out + (size_t)pairIdx * 10200 + (size_t)rowA * 100;
      #pragma unroll
      for (int N = 0; N < 7; N++) {
        f32x4 acc = {0.f,0.f,0.f,0.f};
        acc = __builtin_amdgcn_mfma_f32_16x16x32_f16(w2f[N][0], hb0, acc, 0, 0, 0);
        acc = __builtin_amdgcn_mfma_f32_16x16x32_f16(w2f[N][1], hb1, acc, 0, 0, 0);
        const int colb = 16*N + 4*g;
        if (rowOk && colb < WIN) {
          const float4 bv = b2f[N];
          float4 ov = {fast_tanh(acc[0]+bv.x), fast_tanh(acc[1]+bv.y),
                       fast_tanh(acc[2]+bv.z), fast_tanh(acc[3]+bv.w)};
          *(float4*)&ob[colb] = ov;
        }
      }
    }

    // ---- write next pair's x -> sX (safe: all waves passed bar C => all S1
    // reads of sX(p) are done). Loads issued at bar A have long since landed.
    if (p + 1 < ppb && pairIdx + 1 < nPairs) {
      #define STV2(PV, V) { int row = (V)/25, q4 = ((V)%25)*4; \
        f16x4 hv = {(f16)(PV).x,(f16)(PV).y,(f16)(PV).z,(f16)(PV).w}; \
        *(f16x4*)&sX[row*136 + q4] = hv; }
      STV2(p0, t); STV2(p1, t+512); STV2(p2, t+1024); STV2(p3, t+1536);
      if (t < 502) STV2(p4, t+2048);
      #undef STV2
    }
  }
}

extern "C" void kernel_launch(void* const* d_in, const int* in_sizes, int n_in,
                              void* d_out, int out_size, void* d_ws, size_t ws_size,
                              hipStream_t stream) {
  const float* x     = (const float*)d_in[0];
  const float* embed = (const float*)d_in[2];
  const float* gcn_w = (const float*)d_in[3];
  const float* gcn_b = (const float*)d_in[4];
  const float* w1    = (const float*)d_in[5];
  const float* b1    = (const float*)d_in[6];
  const float* w2    = (const float*)d_in[7];
  const float* b2    = (const float*)d_in[8];
  float* out = (float*)d_out;

  const int batch = in_sizes[0] / (NF * WIN);      // 8192
  const int nPairs = batch / 2;                    // 4096
  const int blocks = 256;
  const int ppb = (nPairs + blocks - 1) / blocks;  // 16

  hipMemsetAsync((char*)d_ws + WS_FLAG, 0, 4, stream);
  fused_kernel<<<blocks, 512, 0, stream>>>(x, embed, gcn_w, gcn_b, w1, b1, w2, b2,
                                           d_ws, out, nPairs, ppb);
}

// Round 14
// 132.765 us; speedup vs baseline: 1.3711x; 1.3711x over previous
//
#include <hip/hip_runtime.h>
#include <hip/hip_bf16.h>
#include <stdint.h>

#define NF 51
#define NF2 (51*51)
#define WIN 100
#define EMB 12
#define FIN 112
#define HID 60
#define NPRUNE 1561
#define SORTN 4096

// ws layout (r3): [LDS-staged: wxT, w1T][register-read: adjT, w2T, D]
#define WS_WX    0          // f16 [112][136] Wx[n][k]  (n<100,k<100 else 0)
#define WS_W1    30464      // f16 [64][136]  w1[n][k]  (n<60,k<100 else 0)
#define WS_ADJ   47872      // f16 [64][72]   adj[m][k] (m,k<51 else 0)
#define WS_W2    57088      // f16 [112][72]  w2[n][k]  (n<100,k<60 else 0)
#define WS_D     73216      // f32 [51][112]  D = norm_adj@C_emb + gcn_b (col<100 else 0)
#define WS_STAGE 47872      // bytes staged to forward LDS (wxT+w1T only)
#define WS_TOTAL 96064

// forward LDS (r3 layout)
#define LDS_WX   0          // f16 [112][136]
#define LDS_W1   30464      // f16 [64][136]
#define LDS_R1X  47872      // f16 [115][136]  sX
#define LDS_R1H  79152      // f16 [115][136]  h2
#define LDS_R2   110432     // f16 yT [2][112][72] / h3 [115][72] (aliased)
#define LDS_TOTAL 142688

typedef _Float16 f16;
typedef _Float16 f16x8 __attribute__((ext_vector_type(8)));
typedef _Float16 f16x4 __attribute__((ext_vector_type(4)));
typedef float f32x4 __attribute__((ext_vector_type(4)));

__device__ __forceinline__ float fast_tanh(float x) {
  float xa = fminf(fmaxf(x, -15.f), 15.f);
  float e = __expf(2.f * xa);
  return (e - 1.f) * __builtin_amdgcn_rcpf(e + 1.f);
}

// T4 barrier: LDS-visibility wait only; vmcnt NOT drained.
#define BAR() do { asm volatile("s_waitcnt lgkmcnt(0)" ::: "memory"); \
  __builtin_amdgcn_s_barrier(); asm volatile("" ::: "memory"); } while (0)

// ---------------- Kernel 1: graph construction + greedy prune + prep ----------------
// block 1 stages wxT/w1T/w2T (prune-independent); block 0: cos -> two-stage
// suspect classification (fast) or sort+walk (fallback) -> adjT/D.
__global__ __launch_bounds__(512) void prune_kernel(const float* __restrict__ embed,
                                                    const float* __restrict__ gcn_w,
                                                    const float* __restrict__ gcn_b,
                                                    const float* __restrict__ w1,
                                                    const float* __restrict__ w2,
                                                    void* __restrict__ ws) {
  const int t = threadIdx.x;
  char* wsb = (char*)ws;

  if (blockIdx.x == 1) {
    f16* wxT = (f16*)(wsb + WS_WX);
    for (int u = t; u < 112*136; u += 512) {
      int nn = u / 136, k = u - nn*136;
      wxT[u] = (f16)((nn < WIN && k < WIN) ? gcn_w[nn*FIN + k] : 0.f);
    }
    f16* w1T = (f16*)(wsb + WS_W1);
    for (int u = t; u < 64*136; u += 512) {
      int nn = u / 136, k = u - nn*136;
      w1T[u] = (f16)((nn < HID && k < WIN) ? w1[nn*WIN + k] : 0.f);
    }
    f16* w2T = (f16*)(wsb + WS_W2);
    for (int u = t; u < 112*72; u += 512) {
      int nn = u / 72, k = u - nn*72;
      w2T[u] = (f16)((nn < WIN && k < HID) ? w2[nn*HID + k] : 0.f);
    }
    return;
  }

  __shared__ float sA[NF * 52];
  __shared__ unsigned long long sKey[SORTN];
  __shared__ float sNrm[NF];
  __shared__ float sDinv[NF];
  __shared__ float sRow[NF];
  __shared__ float sCol[NF];
  __shared__ float sRowS[NF];
  __shared__ float sColS[NF];
  __shared__ float sEmb[NF * EMB];
  __shared__ float sE2[NF * EMB];
  __shared__ unsigned char sMask[NF2];
  __shared__ unsigned long long sSusp[64];
  __shared__ int sCand[256];
  __shared__ int sCnt[17];
  __shared__ int sNS;
  __shared__ int sNC;
  __shared__ int sTotal;

  for (int u = t; u < NF * EMB; u += 512) sEmb[u] = embed[u];
  for (int u = t; u < NF2; u += 512) sMask[u] = 0;
  if (t == 0) { sNS = 0; sNC = 0; sTotal = 0; }
  __syncthreads();
  if (t < NF) {
    float s = 0.f;
    for (int e = 0; e < EMB; e++) { float w = sEmb[t*EMB + e]; s += w * w; }
    sNrm[t] = sqrtf(s);
  }
  __syncthreads();
  for (int u = t; u < NF2; u += 512) {
    int r = u / NF, c = u % NF;
    float d = 0.f;
    for (int e = 0; e < EMB; e++) d += sEmb[r*EMB + e] * sEmb[c*EMB + e];
    sA[r*52 + c] = d / (sNrm[r] * sNrm[c]);
  }
  __syncthreads();

  if (t < NF) {
    float rs = 0.f, cs = 0.f;
    for (int j = 0; j < NF; j++) { rs += sA[t*52 + j]; cs += sA[j*52 + t]; }
    sRow[t] = rs; sCol[t] = cs;
  }
  __syncthreads();

  // ---- STAGE A (cheap): rejection of (r,c,v) requires visit-sum <= v on
  // BOTH axes; sums only increase => sRow0>v || sCol0>v means unconditional
  // accept. Survivors = candidates.
  {
    int myCnt = 0;
    for (int u = t; u < NF2; u += 512) {
      int r = u / NF, c = u % NF;
      float v = sA[r*52 + c];
      if (v < 0.f) {
        myCnt++;
        if (sRow[r] <= v && sCol[c] <= v) {
          int slot = atomicAdd(&sNC, 1);
          if (slot < 256) sCand[slot] = u;
        }
      }
    }
    if (myCnt) atomicAdd(&sTotal, myCnt);
  }
  __syncthreads();
  // ---- STAGE B (sharpened): visit-sum >= S0 + sum(-v_j) over earlier
  // negatives in the row/col (each processed entry contributes >= -v_j).
  // Candidates passing this bound are definitely accepted; rest = suspects.
  if (sNC <= 256) {
    const int nC = sNC;
    for (int i = t; i < nC; i += 512) {
      int u = sCand[i];
      int r = u / NF, c = u - r*NF;
      float v = sA[r*52 + c];
      float Pr = 0.f, Pc = 0.f;
      for (int j = 0; j < NF; j++) {
        float a = sA[r*52 + j];
        if (a < 0.f && (a < v || (a == v && r*NF + j < u))) Pr -= a;
        float b = sA[j*52 + c];
        if (b < 0.f && (b < v || (b == v && j*NF + c < u))) Pc -= b;
      }
      bool okS = ((sRow[r] + Pr - v) > 0.f) || ((sCol[c] + Pc - v) > 0.f);
      if (!okS) {
        int slot = atomicAdd(&sNS, 1);
        if (slot < 64) {
          unsigned int b = __float_as_uint(v);   // negative -> monotone map ~b
          sSusp[slot] = ((unsigned long long)(~b) << 32) | (unsigned int)u;
          sMask[u] = 1;
        }
      }
    }
  }
  __syncthreads();
  const bool fastPath = (sTotal > 0) && (sTotal <= NPRUNE) && (sNC <= 256) && (sNS <= 64);

  if (fastPath) {
    if (t < 64) {
      const int lane = t;
      float mx = -3.0e38f;
      for (int u = lane; u < NF2; u += 64) mx = fmaxf(mx, sA[(u / NF)*52 + (u % NF)]);
      for (int o = 32; o > 0; o >>= 1) mx = fmaxf(mx, __shfl_xor(mx, o, 64));
      if (lane < NF) { sRowS[lane] = 0.f; sColS[lane] = 0.f; }
      const int nS = sNS;
      unsigned long long key = (lane < nS) ? sSusp[lane] : ~0ull;
      // in-wave bitonic sort (64 lanes) ascending (value, idx)
      for (int k = 2; k <= 64; k <<= 1) {
        for (int j = k >> 1; j > 0; j >>= 1) {
          unsigned long long other = __shfl_xor(key, j, 64);
          bool up = ((lane & k) == 0);
          bool takeMin = (((lane & j) == 0) == up);
          unsigned long long mn = key < other ? key : other;
          unsigned long long mxk = key < other ? other : key;
          key = takeMin ? mn : mxk;
        }
      }
      // serial exact walk over suspects
      for (int kk = 0; kk < nS; kk++) {
        unsigned long long kv = __shfl(key, kk, 64);
        unsigned int mb = (unsigned int)(kv >> 32);
        unsigned int idx = (unsigned int)kv;
        float v = __uint_as_float(~mb);            // suspects are negative
        int r = (int)(idx / NF), c = (int)(idx % NF);
        float pr = 0.f, pc = 0.f;
        if (lane < NF) {
          float a = sA[r*52 + lane];
          if (a < 0.f && !sMask[r*NF + lane] &&
              (a < v || (a == v && (unsigned)(r*NF + lane) < idx))) pr = -a;
          float b = sA[lane*52 + c];
          if (b < 0.f && !sMask[lane*NF + c] &&
              (b < v || (b == v && (unsigned)(lane*NF + c) < idx))) pc = -b;
        }
        for (int o = 32; o > 0; o >>= 1) {
          pr += __shfl_xor(pr, o, 64);
          pc += __shfl_xor(pc, o, 64);
        }
        float sumR = sRow[r] + pr + sRowS[r];
        float sumC = sCol[c] + pc + sColS[c];
        bool ok = ((sumR - v) > 0.f) || ((sumC - v) > 0.f);
        if (lane == 0) {
          if (ok) { sA[r*52 + c] = 0.f; sRowS[r] += -v;     sColS[c] += -v; }
          else    { sA[r*52 + c] = mx;  sRowS[r] += mx - v; sColS[c] += mx - v; }
        }
      }
    }
    __syncthreads();
    for (int u = t; u < NF2; u += 512) {
      int r = u / NF, c = u % NF;
      if (sA[r*52 + c] < 0.f) sA[r*52 + c] = 0.f;
    }
  } else {
    // ---- SLOW PATH (exact; compaction + bitonic sort + ballot walk) ----
    int myCnt = 0;
    for (int u = t; u < NF2; u += 512)
      myCnt += (sA[(u / NF)*52 + (u % NF)] < 0.f) ? 1 : 0;
    int incl = myCnt;
    for (int o = 1; o < 64; o <<= 1) {
      int nb = __shfl_up(incl, o, 64);
      if ((t & 63) >= o) incl += nb;
    }
    if ((t & 63) == 63) sCnt[t >> 6] = incl;
    __syncthreads();
    if (t == 0) {
      int run = 0;
      for (int j = 0; j < 8; j++) { int v = sCnt[j]; sCnt[8 + j] = run; run += v; }
      sCnt[16] = run;
    }
    __syncthreads();
    const int total = sCnt[16];
    const int n = (total <= 2048) ? 2048 : SORTN;
    {
      int cpos = sCnt[8 + (t >> 6)] + (incl - myCnt);
      for (int u = t; u < NF2; u += 512) {
        float v = sA[(u / NF)*52 + (u % NF)];
        if (v < 0.f) {
          unsigned int b = __float_as_uint(v);
          sKey[cpos++] = ((unsigned long long)(~b) << 32) | (unsigned int)u;
        }
      }
      for (int u = total + t; u < n; u += 512) sKey[u] = ~0ull;
    }
    __syncthreads();
    for (int kk = 2; kk <= n; kk <<= 1) {
      for (int jj = kk >> 1; jj > 0; jj >>= 1) {
        for (int u = t; u < n; u += 512) {
          int l = u ^ jj;
          if (l > u) {
            unsigned long long a = sKey[u], b = sKey[l];
            bool up = ((u & kk) == 0);
            if ((a > b) == up) { sKey[u] = b; sKey[l] = a; }
          }
        }
        __syncthreads();
      }
    }

    if (t < 64) {
      const int lane = t;
      float mx = -3.0e38f;
      for (int u = lane; u < NF2; u += 64) mx = fmaxf(mx, sA[(u / NF)*52 + (u % NF)]);
      for (int o = 32; o > 0; o >>= 1) mx = fmaxf(mx, __shfl_xor(mx, o, 64));

      int pruned = 0, pos = 0;
      bool toP2 = false;
      while (pruned < NPRUNE && !toP2) {
        int myi = pos + lane;
        unsigned long long kv = (myi < n) ? sKey[myi] : ~0ull;
        unsigned int mb  = (unsigned int)(kv >> 32);
        unsigned int idx = (unsigned int)kv;
        unsigned int vb  = (mb & 0x80000000u) ? (mb & 0x7FFFFFFFu) : ~mb;
        float v = __uint_as_float(vb);
        bool elig = (v < 0.f) && (idx < (unsigned)NF2);
        int r = 0, c2 = 0; bool okl = false;
        if (elig) {
          r = (int)(idx / NF); c2 = (int)(idx % NF);
          float sr = sRow[r], sc = sCol[c2];
          okl = ((sr - v) > 0.f) || ((sc - v) > 0.f);
        }
        unsigned long long bal = __ballot(okl);
        unsigned long long nb = ~bal;
        int nok = (nb == 0ull) ? 64 : (int)__builtin_ctzll(nb);
        int rem = NPRUNE - pruned;
        int take = nok < rem ? nok : rem;
        if (lane < take) {
          sA[r*52 + c2] = 0.f;
          atomicAdd(&sRow[r], -v);
          atomicAdd(&sCol[c2], -v);
        }
        pruned += take; pos += take;
        if (pruned >= NPRUNE) break;
        if (take == 64) continue;
        unsigned int bvb = (unsigned int)__builtin_amdgcn_readlane((int)vb, take);
        int bidx = __builtin_amdgcn_readlane((int)idx, take);
        float bv = __uint_as_float(bvb);
        if (!(bv < 0.f) || bidx >= NF2) { toP2 = true; break; }
        int br = bidx / NF, bc = bidx % NF;
        float sr = sRow[br], sc = sCol[bc];
        bool ok = ((sr - bv) > 0.f) || ((sc - bv) > 0.f);
        if (ok) {
          if (lane == 0) {
            sA[br*52 + bc] = 0.f;
            sRow[br] = sr - bv; sCol[bc] = sc - bv;
          }
          pruned++; pos++;
        } else {
          if (lane == 0) {
            sA[br*52 + bc] = mx;
            sRow[br] = sr + (mx - bv); sCol[bc] = sc + (mx - bv);
          }
          pos++;
        }
      }
      if (toP2) {
        for (int guard = 0; guard < 40000 && pruned < NPRUNE; guard++) {
          float bv = 3.0e38f; int bidx = NF2;
          for (int u = lane; u < NF2; u += 64) {
            float v = sA[(u / NF)*52 + (u % NF)];
            if (v < bv) { bv = v; bidx = u; }
          }
          for (int o = 32; o > 0; o >>= 1) {
            float ov = __shfl_xor(bv, o, 64);
            int  oi = __shfl_xor(bidx, o, 64);
            if (ov < bv || (ov == bv && oi < bidx)) { bv = ov; bidx = oi; }
          }
          int br = bidx / NF, bc = bidx % NF;
          float sr = sRow[br], sc = sCol[bc];
          bool ok = ((sr - bv) > 0.f) || ((sc - bv) > 0.f);
          if (ok) {
            if (bv == 0.f) break;
            if (lane == 0) { sA[br*52+bc] = 0.f; sRow[br] = sr - bv; sCol[bc] = sc - bv; }
            pruned++;
          } else {
            if (bv == mx) break;
            if (lane == 0) { sA[br*52+bc] = mx; sRow[br] = sr + (mx-bv); sCol[bc] = sc + (mx-bv); }
          }
        }
      }
    }
  }
  __syncthreads();

  if (t < NF) {
    float deg = 0.f;
    for (int j = 0; j < NF; j++) {
      float a = sA[t*52 + j];
      float bin = (a != 0.f) ? 1.f : 0.f;
      if (j == t) bin += 1.f;
      deg += bin;
    }
    sDinv[t] = 1.f / sqrtf(deg);
  }
  __syncthreads();

  float* sN = (float*)sKey;   // sKey dead; reuse as norm_adj [51][52]
  for (int u = t; u < NF * 52; u += 512) {
    int r = u / 52, c = u % 52;
    float v = 0.f;
    if (c < NF) {
      float a = sA[r*52 + c];
      float bin = (a != 0.f) ? 1.f : 0.f;
      if (r == c) bin += 1.f;
      v = sDinv[r] * bin * sDinv[c];
    }
    sN[u] = v;
  }
  __syncthreads();

  // E2 = norm_adj @ embed  [51][12]  (D = (norm_adj@embed)@gcn_w_emb^T)
  for (int u = t; u < NF * EMB; u += 512) {
    int i = u / EMB, e = u % EMB;
    float s2 = 0.f;
    for (int j = 0; j < NF; j++) s2 += sN[i*52 + j] * sEmb[j*EMB + e];
    sE2[u] = s2;
  }

  f16* adjT = (f16*)(wsb + WS_ADJ);
  for (int u = t; u < 64*72; u += 512) {
    int r = u / 72, k = u % 72;
    adjT[u] = (f16)((r < NF && k < NF) ? sN[r*52 + k] : 0.f);
  }
  __syncthreads();   // sE2 ready
  float* Dp = (float*)(wsb + WS_D);
  for (int u = t; u < NF * 112; u += 512) {
    int i = u / 112, w = u % 112;
    float s2 = 0.f;
    if (w < WIN) {
      for (int e = 0; e < EMB; e++) s2 += sE2[i*EMB + e] * gcn_w[w*FIN + WIN + e];
      s2 += gcn_b[w];
    }
    Dp[u] = s2;
  }
}

// ---------------- Kernel 2: persistent fused MFMA forward (r10, 115.3us) ----
// 256 blocks x 512 thr; 3 barriers/iter: separate x / h2 buffers remove the
// WAR that needed a 4th; S4 reads only its own wave's h3 (lgkm-wait only).
// adjT/w2T/D/b1/b2 register-resident (~136 persistent VGPR — at the allocator's
// feasible edge; w1 stays in LDS: hoisting it (r11), everything (r9), or fusing
// prune into this kernel (r13, codegen perturbation) all regress).
__global__ __launch_bounds__(512, 1) void forward_kernel(
    const float* __restrict__ x, const float* __restrict__ b1g,
    const float* __restrict__ b2g, const void* __restrict__ ws,
    float* __restrict__ out, int nPairs, int ppb) {
  __shared__ __align__(16) char smem[LDS_TOTAL];
  f16* wxT = (f16*)(smem + LDS_WX);
  f16* w1T = (f16*)(smem + LDS_W1);
  f16* sX  = (f16*)(smem + LDS_R1X);   // [115][136] x rows
  f16* sH  = (f16*)(smem + LDS_R1H);   // [115][136] h2 rows
  f16* yT  = (f16*)(smem + LDS_R2);    // [2][112][72]
  f16* h3  = (f16*)(smem + LDS_R2);    // [115][72] (aliases yT; yT dead by S3)

  const int t = threadIdx.x;
  const int wv = t >> 6, lane = t & 63;
  const int c = lane & 15, g = lane >> 4;
  const int s = wv >> 2, mt = wv & 3;
  const int rowA = 51*s + 16*mt + c;

  // one-time: stage wxT+w1T (47872 B linear), zero x/h2/yT regions
  {
    const f32x4* w4 = (const f32x4*)ws;
    f32x4* s4 = (f32x4*)smem;
    #pragma unroll
    for (int u = 0; u < 6; u++) { int i = t + u*512; if (i < 2992) s4[i] = w4[i]; }
    f32x4 z = {0.f,0.f,0.f,0.f};
    f32x4* za = (f32x4*)(smem + LDS_R1X);
    #pragma unroll
    for (int u = 0; u < 12; u++) { int i = t + u*512; if (i < 5926) za[i] = z; }
  }

  const int pair0 = blockIdx.x * ppb;
  float4 p0, p1, p2, p3, p4;
  if (pair0 < nPairs) {
    const float4* xb = (const float4*)(x + (size_t)pair0 * 10200);
    p0 = xb[t]; p1 = xb[t+512]; p2 = xb[t+1024]; p3 = xb[t+1536];
    if (t < 502) p4 = xb[t+2048];
  }

  // ---- register-resident static data (loaded once from global) ----
  const char* wsb = (const char*)ws;
  const f16* adjG = (const f16*)(wsb + WS_ADJ);
  const f16* w2G  = (const f16*)(wsb + WS_W2);
  const float* DG = (const float*)(wsb + WS_D);

  f16x8 adjf[4][2];
  #pragma unroll
  for (int N = 0; N < 4; N++) {
    const f16* bp = &adjG[(16*N + c)*72 + 8*g];
    adjf[N][0] = *(const f16x8*)(bp + 0);
    adjf[N][1] = *(const f16x8*)(bp + 32);
  }
  f16x8 w2f[7][2];
  #pragma unroll
  for (int N = 0; N < 7; N++) {
    const f16* ap = &w2G[(16*N + c)*72 + 8*g];
    w2f[N][0] = *(const f16x8*)(ap + 0);
    w2f[N][1] = *(const f16x8*)(ap + 32);
  }
  // S2 task split (compile-time per wave): task A = wv (s2a,wta); task B = wv+8
  const int s2a = (wv == 7) ? 1 : 0;
  const int wta = (wv == 7) ? 0 : wv;
  const int wtb = wv + 1;                 // s2 = 1, only wv < 6
  float4 dA[4], dB[4];
  {
    const float4 zf = {0.f,0.f,0.f,0.f};
    #pragma unroll
    for (int N = 0; N < 4; N++) {
      int nd = 16*N + c;
      dA[N] = (nd < NF) ? *(const float4*)&DG[nd*112 + 16*wta + 4*g] : zf;
      dB[N] = (wv < 6 && nd < NF) ? *(const float4*)&DG[nd*112 + 16*wtb + 4*g] : zf;
    }
  }
  float4 b1f[4], b2f[7];
  {
    const float4 zf = {0.f,0.f,0.f,0.f};
    #pragma unroll
    for (int N = 0; N < 4; N++) {
      int colb = 16*N + 4*g;
      b1f[N] = (colb < HID) ? *(const float4*)&b1g[colb] : zf;
    }
    #pragma unroll
    for (int N = 0; N < 7; N++) {
      int colb = 16*N + 4*g;
      b2f[N] = (colb < WIN) ? *(const float4*)&b2g[colb] : zf;
    }
  }
  __syncthreads();

  // prologue: write sX(pair0)
  if (pair0 < nPairs) {
    #define STV(PV, V) { int row = (V)/25, q4 = ((V)%25)*4; \
      f16x4 hv = {(f16)(PV).x,(f16)(PV).y,(f16)(PV).z,(f16)(PV).w}; \
      *(f16x4*)&sX[row*136 + q4] = hv; }
    STV(p0, t); STV(p1, t+512); STV(p2, t+1024); STV(p3, t+1536);
    if (t < 502) STV(p4, t+2048);
  }

  #pragma unroll 1
  for (int p = 0; p < ppb; p++) {
    const int pairIdx = pair0 + p;
    const bool valid = pairIdx < nPairs;

    BAR();   // bar A: sX(p) ready (written end of prev iter / prologue)

    // issue next pair's prefetch (consumed at iter end; spans S1..S4)
    if (p + 1 < ppb && pairIdx + 1 < nPairs) {
      const float4* xb = (const float4*)(x + (size_t)(pairIdx+1) * 10200);
      p0 = xb[t]; p1 = xb[t+512]; p2 = xb[t+1024]; p3 = xb[t+1536];
      if (t < 502) p4 = xb[t+2048];
    }

    // ---- S1: y = x @ Wx^T ; write yT[s][win][node] (transposed, b64) ----
    if (valid) {
      const f16* aB = &sX[rowA*136];
      const f16x8 a0 = *(const f16x8*)(aB +  0 + 8*g);
      const f16x8 a1 = *(const f16x8*)(aB + 32 + 8*g);
      const f16x8 a2 = *(const f16x8*)(aB + 64 + 8*g);
      const f16x8 a3 = *(const f16x8*)(aB + 96 + 8*g);
      f16* yTs = yT + s*8064;
      const int nodeW = 16*mt + 4*g;
      #pragma unroll
      for (int N = 0; N < 7; N++) {
        const f16* bp = &wxT[(16*N + c)*136 + 8*g];
        f32x4 acc = {0.f,0.f,0.f,0.f};
        acc = __builtin_amdgcn_mfma_f32_16x16x32_f16(a0, *(const f16x8*)(bp +  0), acc, 0, 0, 0);
        acc = __builtin_amdgcn_mfma_f32_16x16x32_f16(a1, *(const f16x8*)(bp + 32), acc, 0, 0, 0);
        acc = __builtin_amdgcn_mfma_f32_16x16x32_f16(a2, *(const f16x8*)(bp + 64), acc, 0, 0, 0);
        acc = __builtin_amdgcn_mfma_f32_16x16x32_f16(a3, *(const f16x8*)(bp + 96), acc, 0, 0, 0);
        const int col = 16*N + c;
        if (mt < 3) {
          f16x4 hv = {(f16)acc[0],(f16)acc[1],(f16)acc[2],(f16)acc[3]};
          *(f16x4*)&yTs[col*72 + nodeW] = hv;
        } else {
          #pragma unroll
          for (int r2 = 0; r2 < 4; r2++)
            if (nodeW + r2 < NF) yTs[col*72 + nodeW + r2] = (f16)acc[r2];
        }
      }
    }
    BAR();   // bar B: yT ready; sX reads done

    // ---- S2 (swapped): h2 = relu(adj @ y + D) -> sH, b64 writes ----
    if (valid) {
      {
        const f16* ap = &yT[s2a*8064 + (16*wta + c)*72 + 8*g];
        const f16x8 a0 = *(const f16x8*)(ap + 0);
        const f16x8 a1 = *(const f16x8*)(ap + 32);
        #pragma unroll
        for (int N = 0; N < 4; N++) {
          f32x4 acc = {0.f,0.f,0.f,0.f};
          acc = __builtin_amdgcn_mfma_f32_16x16x32_f16(a0, adjf[N][0], acc, 0, 0, 0);
          acc = __builtin_amdgcn_mfma_f32_16x16x32_f16(a1, adjf[N][1], acc, 0, 0, 0);
          const int nd = 16*N + c;
          if (nd < NF) {
            const float4 dv = dA[N];
            f16x4 hv = {(f16)fmaxf(acc[0]+dv.x,0.f),(f16)fmaxf(acc[1]+dv.y,0.f),
                        (f16)fmaxf(acc[2]+dv.z,0.f),(f16)fmaxf(acc[3]+dv.w,0.f)};
            *(f16x4*)&sH[(51*s2a + nd)*136 + 16*wta + 4*g] = hv;
          }
        }
      }
      if (wv < 6) {
        const f16* ap = &yT[8064 + (16*wtb + c)*72 + 8*g];
        const f16x8 a0 = *(const f16x8*)(ap + 0);
        const f16x8 a1 = *(const f16x8*)(ap + 32);
        #pragma unroll
        for (int N = 0; N < 4; N++) {
          f32x4 acc = {0.f,0.f,0.f,0.f};
          acc = __builtin_amdgcn_mfma_f32_16x16x32_f16(a0, adjf[N][0], acc, 0, 0, 0);
          acc = __builtin_amdgcn_mfma_f32_16x16x32_f16(a1, adjf[N][1], acc, 0, 0, 0);
          const int nd = 16*N + c;
          if (nd < NF) {
            const float4 dv = dB[N];
            f16x4 hv = {(f16)fmaxf(acc[0]+dv.x,0.f),(f16)fmaxf(acc[1]+dv.y,0.f),
                        (f16)fmaxf(acc[2]+dv.z,0.f),(f16)fmaxf(acc[3]+dv.w,0.f)};
            *(f16x4*)&sH[(51 + nd)*136 + 16*wtb + 4*g] = hv;
          }
        }
      }
    }
    BAR();   // bar C: h2 ready; yT reads done

    // ---- S3 (swapped): h3 = tanh(h2 @ w1^T + b1) -> R2, b64 writes ----
    if (valid) {
      const f16* bB = &sH[rowA*136 + 8*g];
      const f16x8 hb0 = *(const f16x8*)(bB +  0);
      const f16x8 hb1 = *(const f16x8*)(bB + 32);
      const f16x8 hb2 = *(const f16x8*)(bB + 64);
      const f16x8 hb3 = *(const f16x8*)(bB + 96);
      #pragma unroll
      for (int N = 0; N < 4; N++) {
        const f16* ap = &w1T[(16*N + c)*136 + 8*g];
        f32x4 acc = {0.f,0.f,0.f,0.f};
        acc = __builtin_amdgcn_mfma_f32_16x16x32_f16(*(const f16x8*)(ap +  0), hb0, acc, 0, 0, 0);
        acc = __builtin_amdgcn_mfma_f32_16x16x32_f16(*(const f16x8*)(ap + 32), hb1, acc, 0, 0, 0);
        acc = __builtin_amdgcn_mfma_f32_16x16x32_f16(*(const f16x8*)(ap + 64), hb2, acc, 0, 0, 0);
        acc = __builtin_amdgcn_mfma_f32_16x16x32_f16(*(const f16x8*)(ap + 96), hb3, acc, 0, 0, 0);
        const int colb = 16*N + 4*g;
        const float4 bv = b1f[N];
        f16x4 hv = {(f16)fast_tanh(acc[0]+bv.x),(f16)fast_tanh(acc[1]+bv.y),
                    (f16)fast_tanh(acc[2]+bv.z),(f16)fast_tanh(acc[3]+bv.w)};
        *(f16x4*)&h3[rowA*72 + colb] = hv;
      }
    }
    // No barrier: S4 consumes ONLY rows written by this same wave in S3.
    asm volatile("s_waitcnt lgkmcnt(0)" ::: "memory");
    __builtin_amdgcn_sched_barrier(0);

    // ---- S4 (swapped): out = tanh(h3 @ w2^T + b2) -> coalesced float4 ----
    if (valid) {
      const f16* bB = &h3[rowA*72 + 8*g];
      const f16x8 hb0 = *(const f16x8*)(bB +  0);
      const f16x8 hb1 = *(const f16x8*)(bB + 32);
      const bool rowOk = (16*mt + c) < NF;
      float* ob = out + (size_t)pairIdx * 10200 + (size_t)rowA * 100;
      #pragma unroll
      for (int N = 0; N < 7; N++) {
        f32x4 acc = {0.f,0.f,0.f,0.f};
        acc = __builtin_amdgcn_mfma_f32_16x16x32_f16(w2f[N][0], hb0, acc, 0, 0, 0);
        acc = __builtin_amdgcn_mfma_f32_16x16x32_f16(w2f[N][1], hb1, acc, 0, 0, 0);
        const int colb = 16*N + 4*g;
        if (rowOk && colb < WIN) {
          const float4 bv = b2f[N];
          float4 ov = {fast_tanh(acc[0]+bv.x), fast_tanh(acc[1]+bv.y),
                       fast_tanh(acc[2]+bv.z), fast_tanh(acc[3]+bv.w)};
          *(float4*)&ob[colb] = ov;
        }
      }
    }

    // ---- write next pair's x -> sX (safe: all waves passed bar C => all S1
    // reads of sX(p) are done). Loads issued at bar A have long since landed.
    if (p + 1 < ppb && pairIdx + 1 < nPairs) {
      #define STV2(PV, V) { int row = (V)/25, q4 = ((V)%25)*4; \
        f16x4 hv = {(f16)(PV).x,(f16)(PV).y,(f16)(PV).z,(f16)(PV).w}; \
        *(f16x4*)&sX[row*136 + q4] = hv; }
      STV2(p0, t); STV2(p1, t+512); STV2(p2, t+1024); STV2(p3, t+1536);
      if (t < 502) STV2(p4, t+2048);
      #undef STV2
    }
  }
}

extern "C" void kernel_launch(void* const* d_in, const int* in_sizes, int n_in,
                              void* d_out, int out_size, void* d_ws, size_t ws_size,
                              hipStream_t stream) {
  const float* x     = (const float*)d_in[0];
  const float* embed = (const float*)d_in[2];
  const float* gcn_w = (const float*)d_in[3];
  const float* gcn_b = (const float*)d_in[4];
  const float* w1    = (const float*)d_in[5];
  const float* b1    = (const float*)d_in[6];
  const float* w2    = (const float*)d_in[7];
  const float* b2    = (const float*)d_in[8];
  float* out = (float*)d_out;

  const int batch = in_sizes[0] / (NF * WIN);   // 8192
  const int nPairs = batch / 2;                 // 4096
  const int blocks = 256;
  const int ppb = (nPairs + blocks - 1) / blocks;  // 16

  prune_kernel<<<2, 512, 0, stream>>>(embed, gcn_w, gcn_b, w1, w2, d_ws);
  forward_kernel<<<blocks, 512, 0, stream>>>(x, b1, b2, d_ws, out, nPairs, ppb);
}